// Round 1
// baseline (668.106 us; speedup 1.0000x reference)
//
#include <hip/hip_runtime.h>
#include <hip/hip_bf16.h>

// Problem constants (B=16, L=2048, D=1024, K=3)
#define D_    1024
#define LSEQ  2048
#define BATCH 16
#define M_    (BATCH * LSEQ)   // 32768 rows
#define K_    1024             // reduction dim
#define N1    3072             // 3*D output channels of GEMM1

typedef __bf16 bf16x8 __attribute__((ext_vector_type(8)));
typedef float  f32x4  __attribute__((ext_vector_type(4)));
typedef unsigned short us8 __attribute__((ext_vector_type(8)));

__device__ __forceinline__ unsigned short f2bf(float f) {
  unsigned u = __float_as_uint(f);
  u += 0x7FFFu + ((u >> 16) & 1u);   // round-to-nearest-even
  return (unsigned short)(u >> 16);
}

__device__ __forceinline__ float bf2f(unsigned short h) {
  return __uint_as_float(((unsigned)h) << 16);
}

// ---------------- fp32 -> bf16 conversion (vectorized) ----------------
__global__ __launch_bounds__(256) void cvt_f32_bf16(const float* __restrict__ in,
                                                    unsigned short* __restrict__ out,
                                                    int n4) {
  int i = blockIdx.x * 256 + threadIdx.x;
  if (i < n4) {
    float4 v = ((const float4*)in)[i];
    ushort4 o;
    o.x = f2bf(v.x); o.y = f2bf(v.y); o.z = f2bf(v.z); o.w = f2bf(v.w);
    ((ushort4*)out)[i] = o;
  }
}

// ---------------- m97-style bf16 GEMM: C[M,N] = A[M,K] * B[N,K]^T + bias ----------------
#define BM 128
#define BN 128
#define BK 32

__device__ __forceinline__ void gload_lds16(const void* g, void* l) {
  __builtin_amdgcn_global_load_lds((const __attribute__((address_space(1))) void*)g,
                                   (__attribute__((address_space(3))) void*)l,
                                   16, 0, 0);
}

template <int OUT_BF16>
__global__ __launch_bounds__(256) void gemm_bt(const unsigned short* __restrict__ A,
                                               const unsigned short* __restrict__ B,
                                               const float* __restrict__ bias,
                                               void* __restrict__ Cv,
                                               int M, int N, int K) {
  __shared__ unsigned short As[BM * BK];  // 8 KB, row-major [128][32]
  __shared__ unsigned short Bs[BN * BK];  // 8 KB

  const int tid  = threadIdx.x;
  const int lane = tid & 63;
  const int wave = tid >> 6;
  const int quad = lane >> 4;
  const int l16  = lane & 15;
  const int wm   = wave & 1;   // 2x2 wave grid, each wave 64x64
  const int wn   = wave >> 1;
  const int m0   = blockIdx.y * BM;
  const int n0   = blockIdx.x * BN;

  // Staging: flat 16B-chunk id f = issue*256 + tid; row = f>>2, seg = f&3.
  // LDS layout lands exactly row-major [128][32] (wave-uniform base + lane*16).
  const int r0 = tid >> 2;
  const int s0 = (tid & 3) * 8;
  const unsigned short* a0 = A + (long)(m0 + r0) * K + s0;
  const unsigned short* a1 = a0 + (long)64 * K;
  const unsigned short* b0 = B + (long)(n0 + r0) * K + s0;
  const unsigned short* b1 = b0 + (long)64 * K;
  unsigned short* lA0 = &As[tid * 8];
  unsigned short* lA1 = &As[(256 + tid) * 8];
  unsigned short* lB0 = &Bs[tid * 8];
  unsigned short* lB1 = &Bs[(256 + tid) * 8];

  f32x4 acc[4][4] = {};

  for (int k0 = 0; k0 < K; k0 += BK) {
    gload_lds16(a0 + k0, lA0);
    gload_lds16(a1 + k0, lA1);
    gload_lds16(b0 + k0, lB0);
    gload_lds16(b1 + k0, lB1);
    __syncthreads();  // compiler emits vmcnt(0) drain before s_barrier

    bf16x8 af[4], bfr[4];
#pragma unroll
    for (int mi = 0; mi < 4; ++mi)
      af[mi] = *(const bf16x8*)&As[(wm * 64 + mi * 16 + l16) * BK + quad * 8];
#pragma unroll
    for (int ni = 0; ni < 4; ++ni)
      bfr[ni] = *(const bf16x8*)&Bs[(wn * 64 + ni * 16 + l16) * BK + quad * 8];

#pragma unroll
    for (int mi = 0; mi < 4; ++mi)
#pragma unroll
      for (int ni = 0; ni < 4; ++ni)
        acc[mi][ni] = __builtin_amdgcn_mfma_f32_16x16x32_bf16(af[mi], bfr[ni],
                                                              acc[mi][ni], 0, 0, 0);
    __syncthreads();
  }

  // Epilogue: D layout row = quad*4 + r, col = lane&15 (measured m89/m91)
#pragma unroll
  for (int ni = 0; ni < 4; ++ni) {
    int col = n0 + wn * 64 + ni * 16 + l16;
    float bv = bias[col];
#pragma unroll
    for (int mi = 0; mi < 4; ++mi) {
      int row = m0 + wm * 64 + mi * 16 + quad * 4;
      f32x4 v = acc[mi][ni];
#pragma unroll
      for (int r = 0; r < 4; ++r) {
        float o = v[r] + bv;
        if (OUT_BF16)
          ((unsigned short*)Cv)[(long)(row + r) * N + col] = f2bf(o);
        else
          ((float*)Cv)[(long)(row + r) * N + col] = o;
      }
    }
  }
}

// ---------------- causal depthwise conv + gating ----------------
// y[b,l,d] = Cg[b,l,d] * (w0*Bx[b,l-2,d] + w1*Bx[b,l-1,d] + w2*Bx[b,l,d])
// Bx = Bg*xg recomputed from BCx (chunks: Bg at +0, Cg at +1024, xg at +2048)
__global__ __launch_bounds__(256) void conv_mul(const unsigned short* __restrict__ BCx,
                                                const float* __restrict__ wconv,
                                                unsigned short* __restrict__ y) {
  __shared__ float wt[3][D_];  // transposed wconv, 12 KB
  for (int i = threadIdx.x; i < D_; i += 256) {
    wt[0][i] = wconv[i * 3 + 0];
    wt[1][i] = wconv[i * 3 + 1];
    wt[2][i] = wconv[i * 3 + 2];
  }
  __syncthreads();

  int idx = blockIdx.x * 256 + threadIdx.x;  // [0, 32768*128)
  int bl  = idx >> 7;
  int d8  = (idx & 127) * 8;
  int l   = bl & (LSEQ - 1);
  const unsigned short* row = BCx + (long)bl * N1;

  us8 bg0 = *(const us8*)&row[d8];
  us8 xg0 = *(const us8*)&row[2048 + d8];
  us8 cg  = *(const us8*)&row[1024 + d8];

  float bx0[8], bx1[8], bx2[8];
#pragma unroll
  for (int j = 0; j < 8; ++j) { bx0[j] = bf2f(bg0[j]) * bf2f(xg0[j]); bx1[j] = 0.f; bx2[j] = 0.f; }

  if (l >= 1) {
    us8 bg1 = *(const us8*)&row[-N1 + d8];
    us8 xg1 = *(const us8*)&row[-N1 + 2048 + d8];
#pragma unroll
    for (int j = 0; j < 8; ++j) bx1[j] = bf2f(bg1[j]) * bf2f(xg1[j]);
  }
  if (l >= 2) {
    us8 bg2 = *(const us8*)&row[-2 * N1 + d8];
    us8 xg2 = *(const us8*)&row[-2 * N1 + 2048 + d8];
#pragma unroll
    for (int j = 0; j < 8; ++j) bx2[j] = bf2f(bg2[j]) * bf2f(xg2[j]);
  }

  us8 outv;
#pragma unroll
  for (int j = 0; j < 8; ++j) {
    float conv = wt[0][d8 + j] * bx2[j] + wt[1][d8 + j] * bx1[j] + wt[2][d8 + j] * bx0[j];
    outv[j] = f2bf(bf2f(cg[j]) * conv);
  }
  *(us8*)&y[(long)bl * D_ + d8] = outv;
}

// ---------------- launch ----------------
extern "C" void kernel_launch(void* const* d_in, const int* in_sizes, int n_in,
                              void* d_out, int out_size, void* d_ws, size_t ws_size,
                              hipStream_t stream) {
  const float* x     = (const float*)d_in[0];
  const float* Win   = (const float*)d_in[1];
  const float* bin   = (const float*)d_in[2];
  const float* wconv = (const float*)d_in[3];
  const float* Wout  = (const float*)d_in[4];
  const float* bout  = (const float*)d_in[5];

  char* ws = (char*)d_ws;
  // ws layout (bytes):
  //   x_b    @ 0          : 32768*1024*2  =  67,108,864
  //   Win_b  @ 67108864   :  3072*1024*2  =   6,291,456
  //   Wout_b @ 73400320   :  1024*1024*2  =   2,097,152
  //   BCx_b  @ 75497472   : 32768*3072*2  = 201,326,592
  //   y_b    @ 276824064  : 32768*1024*2  =  67,108,864
  // total 343,932,928
  unsigned short* x_b    = (unsigned short*)(ws);
  unsigned short* Win_b  = (unsigned short*)(ws + 67108864);
  unsigned short* Wout_b = (unsigned short*)(ws + 73400320);
  unsigned short* BCx_b  = (unsigned short*)(ws + 75497472);
  unsigned short* y_b    = (unsigned short*)(ws + 276824064);

  // converts
  cvt_f32_bf16<<<(M_ * K_ / 4) / 256, 256, 0, stream>>>(x, x_b, M_ * K_ / 4);
  cvt_f32_bf16<<<(N1 * K_ / 4) / 256, 256, 0, stream>>>(Win, Win_b, N1 * K_ / 4);
  cvt_f32_bf16<<<(D_ * K_ / 4) / 256, 256, 0, stream>>>(Wout, Wout_b, D_ * K_ / 4);

  // GEMM1: BCx = x * Win^T + bin  -> bf16
  {
    dim3 grid(N1 / BN, M_ / BM);
    gemm_bt<1><<<grid, 256, 0, stream>>>(x_b, Win_b, bin, BCx_b, M_, N1, K_);
  }

  // conv + gating -> y bf16
  conv_mul<<<(M_ * (D_ / 8)) / 256, 256, 0, stream>>>(BCx_b, wconv, y_b);

  // GEMM2: out = y * Wout^T + bout -> fp32
  {
    dim3 grid(D_ / BN, M_ / BM);
    gemm_bt<0><<<grid, 256, 0, stream>>>(y_b, Wout_b, bout, d_out, M_, D_, K_);
  }
}

// Round 2
// 631.406 us; speedup vs baseline: 1.0581x; 1.0581x over previous
//
#include <hip/hip_runtime.h>
#include <hip/hip_bf16.h>

// Problem constants (B=16, L=2048, D=1024, K=3)
#define D_    1024
#define LSEQ  2048
#define M_    32768            // B*L rows
#define K_    1024             // reduction dim

typedef __bf16 bf16x8 __attribute__((ext_vector_type(8)));
typedef float  f32x4  __attribute__((ext_vector_type(4)));

__device__ __forceinline__ unsigned short f2bf(float f) {
  unsigned u = __float_as_uint(f);
  u += 0x7FFFu + ((u >> 16) & 1u);   // RNE
  return (unsigned short)(u >> 16);
}
__device__ __forceinline__ float bf2f(unsigned short h) {
  return __uint_as_float(((unsigned)h) << 16);
}

// ---------------- fp32 -> bf16 conversion ----------------
__global__ __launch_bounds__(256) void cvt_f32_bf16(const float* __restrict__ in,
                                                    unsigned short* __restrict__ out,
                                                    int n4) {
  int i = blockIdx.x * 256 + threadIdx.x;
  if (i < n4) {
    float4 v = ((const float4*)in)[i];
    ushort4 o;
    o.x = f2bf(v.x); o.y = f2bf(v.y); o.z = f2bf(v.z); o.w = f2bf(v.w);
    ((ushort4*)out)[i] = o;
  }
}

// ---------------- fused bf16 GEMM family ----------------
// C[M,128-tile] = A[M,K] * [B0 rows; B1 rows]^T, m97 structure (BM=BN=128, BK=32).
// MODE 0: Bx-GEMM  — B0=W_B rows d0.., B1=W_x rows d0.. ; epilogue Bx=(Bg+b)(xg+b) -> bf16 [M,1024]
// MODE 1: Cg-GEMM  — B = W_C rows;      epilogue y = Cg * causal_conv(Bx) -> bf16 [M,1024]
// MODE 2: out-GEMM — B = Wout;          epilogue fp32 + bout -> d_out [M,1024]
#define BK 32

__device__ __forceinline__ void gload_lds16(const void* g, void* l) {
  __builtin_amdgcn_global_load_lds((const __attribute__((address_space(1))) void*)g,
                                   (__attribute__((address_space(3))) void*)l,
                                   16, 0, 0);
}

template <int MODE>
__global__ __launch_bounds__(256) void gemm_fused(const unsigned short* __restrict__ A,
                                                  const unsigned short* __restrict__ Wb,   // bf16 weights base
                                                  const float* __restrict__ biasA,
                                                  const float* __restrict__ biasB,         // MODE 0 only (xg bias)
                                                  const unsigned short* __restrict__ Bx,   // MODE 1 only
                                                  const float* __restrict__ wconv,         // MODE 1 only
                                                  void* __restrict__ Outv) {
  __shared__ __align__(16) char smem[16896];     // K-loop: As(8K)+Bs(8K); epilogue: tr 32x132 fp32
  unsigned short* As = (unsigned short*)smem;
  unsigned short* Bs = (unsigned short*)(smem + 8192);
  float* tr = (float*)smem;

  const int tid  = threadIdx.x;
  const int lane = tid & 63;
  const int wave = tid >> 6;
  const int quad = lane >> 4;
  const int l16  = lane & 15;
  const int wm   = wave & 1;
  const int wn   = wave >> 1;
  const int m0   = blockIdx.y * 128;

  // B tile base rows (two 64-row halves)
  const unsigned short* B0p;
  const unsigned short* B1p;
  int n0;                       // output col base (width 64 for MODE0, 128 otherwise)
  if (MODE == 0) {
    n0  = blockIdx.x * 64;
    B0p = Wb + (long)n0 * K_;              // W_B rows (Win rows 0..1023)
    B1p = Wb + (long)(2048 + n0) * K_;     // W_x rows (Win rows 2048..3071)
  } else if (MODE == 1) {
    n0  = blockIdx.x * 128;
    B0p = Wb + (long)(1024 + n0) * K_;     // W_C rows
    B1p = B0p + (long)64 * K_;
  } else {
    n0  = blockIdx.x * 128;
    B0p = Wb + (long)n0 * K_;              // Wout rows
    B1p = B0p + (long)64 * K_;
  }

  // staging map: flat chunk f = tid; row=f>>2, seg=f&3 (16B each) -> row-major [128][32]
  const int r0 = tid >> 2;
  const int s0 = (tid & 3) * 8;
  const unsigned short* a0 = A + (long)(m0 + r0) * K_ + s0;
  const unsigned short* a1 = a0 + (long)64 * K_;
  const unsigned short* b0 = B0p + (long)r0 * K_ + s0;
  const unsigned short* b1 = B1p + (long)r0 * K_ + s0;
  unsigned short* lA0 = &As[tid * 8];
  unsigned short* lA1 = &As[(256 + tid) * 8];
  unsigned short* lB0 = &Bs[tid * 8];
  unsigned short* lB1 = &Bs[(256 + tid) * 8];

  f32x4 acc[4][4] = {};

  for (int k0 = 0; k0 < K_; k0 += BK) {
    gload_lds16(a0 + k0, lA0);
    gload_lds16(a1 + k0, lA1);
    gload_lds16(b0 + k0, lB0);
    gload_lds16(b1 + k0, lB1);
    __syncthreads();

    bf16x8 af[4], bfr[4];
#pragma unroll
    for (int mi = 0; mi < 4; ++mi)
      af[mi] = *(const bf16x8*)&As[(wm * 64 + mi * 16 + l16) * BK + quad * 8];
#pragma unroll
    for (int ni = 0; ni < 4; ++ni)
      bfr[ni] = *(const bf16x8*)&Bs[(wn * 64 + ni * 16 + l16) * BK + quad * 8];

#pragma unroll
    for (int mi = 0; mi < 4; ++mi)
#pragma unroll
      for (int ni = 0; ni < 4; ++ni)
        acc[mi][ni] = __builtin_amdgcn_mfma_f32_16x16x32_bf16(af[mi], bfr[ni],
                                                              acc[mi][ni], 0, 0, 0);
    __syncthreads();
  }

  // ---- epilogue: LDS transpose + fused math + vectorized stores ----
  // bias per ni (write-side col = wn*64 + ni*16 + l16)
  float bv[4];
#pragma unroll
  for (int ni = 0; ni < 4; ++ni) {
    int col = wn * 64 + ni * 16 + l16;
    if (MODE == 0)
      bv[ni] = (col < 64) ? biasA[n0 + col] : biasB[n0 + col - 64];
    else
      bv[ni] = biasA[n0 + col];
  }

  const int rr   = tid >> 3;                    // read-side row 0..31
  const int cgid = tid & 7;                     // read-side col group

#pragma unroll
  for (int mi = 0; mi < 4; ++mi) {
    // write acc strip (rows wm*16+quad*4+r of this 32-row chunk) to tr[row][col]
#pragma unroll
    for (int ni = 0; ni < 4; ++ni) {
      int col = wn * 64 + ni * 16 + l16;
      f32x4 v = acc[mi][ni];
#pragma unroll
      for (int r = 0; r < 4; ++r)
        tr[(wm * 16 + quad * 4 + r) * 132 + col] = v[r] + bv[ni];
    }
    __syncthreads();

    int grow = m0 + (rr >> 4) * 64 + mi * 16 + (rr & 15);   // global output row

    if (MODE == 0) {
      unsigned short* Out = (unsigned short*)Outv;
#pragma unroll
      for (int j = 0; j < 2; ++j) {
        int c = (cgid + j * 8) * 4;                         // 0..60, 4 cols
        f32x4 bg = *(const f32x4*)&tr[rr * 132 + c];
        f32x4 xg = *(const f32x4*)&tr[rr * 132 + 64 + c];
        ushort4 o;
        o.x = f2bf(bg[0] * xg[0]); o.y = f2bf(bg[1] * xg[1]);
        o.z = f2bf(bg[2] * xg[2]); o.w = f2bf(bg[3] * xg[3]);
        *(ushort4*)&Out[(long)grow * D_ + n0 + c] = o;
      }
    } else if (MODE == 1) {
      unsigned short* Y = (unsigned short*)Outv;
      int l = grow & (LSEQ - 1);
#pragma unroll
      for (int j = 0; j < 4; ++j) {
        int c = (cgid + j * 8) * 4;
        int d = n0 + c;                                     // multiple of 4
        f32x4 cg = *(const f32x4*)&tr[rr * 132 + c];
        // wconv[d..d+3][0..2] = 12 consecutive floats, 16B-aligned (d%4==0 -> 48k bytes)
        f32x4 w0 = *(const f32x4*)&wconv[d * 3];
        f32x4 w1 = *(const f32x4*)&wconv[d * 3 + 4];
        f32x4 w2 = *(const f32x4*)&wconv[d * 3 + 8];
        float wk0[4] = {w0[0], w0[3], w1[2], w2[1]};        // w[d+i][0]
        float wk1[4] = {w0[1], w1[0], w1[3], w2[2]};        // w[d+i][1]
        float wk2[4] = {w0[2], w1[1], w2[0], w2[3]};        // w[d+i][2]
        ushort4 zz = {0, 0, 0, 0};
        ushort4 x0 = *(const ushort4*)&Bx[(long)grow * D_ + d];              // Bx[l]
        ushort4 x1 = (l >= 1) ? *(const ushort4*)&Bx[(long)(grow - 1) * D_ + d] : zz;
        ushort4 x2 = (l >= 2) ? *(const ushort4*)&Bx[(long)(grow - 2) * D_ + d] : zz;
        ushort4 o;
        o.x = f2bf(cg[0] * (wk0[0] * bf2f(x2.x) + wk1[0] * bf2f(x1.x) + wk2[0] * bf2f(x0.x)));
        o.y = f2bf(cg[1] * (wk0[1] * bf2f(x2.y) + wk1[1] * bf2f(x1.y) + wk2[1] * bf2f(x0.y)));
        o.z = f2bf(cg[2] * (wk0[2] * bf2f(x2.z) + wk1[2] * bf2f(x1.z) + wk2[2] * bf2f(x0.z)));
        o.w = f2bf(cg[3] * (wk0[3] * bf2f(x2.w) + wk1[3] * bf2f(x1.w) + wk2[3] * bf2f(x0.w)));
        *(ushort4*)&Y[(long)grow * D_ + d] = o;
      }
    } else {
      float* Out = (float*)Outv;
#pragma unroll
      for (int j = 0; j < 4; ++j) {
        int c = (cgid + j * 8) * 4;
        f32x4 v = *(const f32x4*)&tr[rr * 132 + c];
        *(f32x4*)&Out[(long)grow * D_ + n0 + c] = v;
      }
    }
    __syncthreads();
  }
}

// ---------------- launch ----------------
extern "C" void kernel_launch(void* const* d_in, const int* in_sizes, int n_in,
                              void* d_out, int out_size, void* d_ws, size_t ws_size,
                              hipStream_t stream) {
  const float* x     = (const float*)d_in[0];
  const float* Win   = (const float*)d_in[1];
  const float* bin   = (const float*)d_in[2];
  const float* wconv = (const float*)d_in[3];
  const float* Wout  = (const float*)d_in[4];
  const float* bout  = (const float*)d_in[5];

  char* ws = (char*)d_ws;
  // ws layout: x_b 67,108,864 | Win_b 6,291,456 | Wout_b 2,097,152 | Bx 67,108,864 | y 67,108,864
  unsigned short* x_b    = (unsigned short*)(ws);
  unsigned short* Win_b  = (unsigned short*)(ws + 67108864);
  unsigned short* Wout_b = (unsigned short*)(ws + 73400320);
  unsigned short* Bx_b   = (unsigned short*)(ws + 75497472);
  unsigned short* y_b    = (unsigned short*)(ws + 142606336);

  cvt_f32_bf16<<<(M_ * K_ / 4) / 256, 256, 0, stream>>>(x, x_b, M_ * K_ / 4);
  cvt_f32_bf16<<<(3072 * K_ / 4) / 256, 256, 0, stream>>>(Win, Win_b, 3072 * K_ / 4);
  cvt_f32_bf16<<<(D_ * K_ / 4) / 256, 256, 0, stream>>>(Wout, Wout_b, D_ * K_ / 4);

  // Bx = (x WB^T + bB) .* (x Wx^T + bx)  -> bf16 [M, 1024]
  {
    dim3 grid(D_ / 64, M_ / 128);
    gemm_fused<0><<<grid, 256, 0, stream>>>(x_b, Win_b, bin, bin + 2048,
                                            nullptr, nullptr, Bx_b);
  }
  // y = (x WC^T + bC) .* causal_conv3(Bx)  -> bf16 [M, 1024]
  {
    dim3 grid(D_ / 128, M_ / 128);
    gemm_fused<1><<<grid, 256, 0, stream>>>(x_b, Win_b, bin + 1024, nullptr,
                                            Bx_b, wconv, y_b);
  }
  // out = y Wout^T + bout -> fp32
  {
    dim3 grid(D_ / 128, M_ / 128);
    gemm_fused<2><<<grid, 256, 0, stream>>>(y_b, Wout_b, bout, nullptr,
                                            nullptr, nullptr, d_out);
  }
}

// Round 4
// 594.276 us; speedup vs baseline: 1.1242x; 1.0625x over previous
//
#include <hip/hip_runtime.h>
#include <hip/hip_bf16.h>

// Problem constants (B=16, L=2048, D=1024, K=3)
#define D_    1024
#define LSEQ  2048
#define M_    32768            // B*L rows
#define K_    1024             // reduction dim
#define BK    32

typedef __bf16 bf16x8 __attribute__((ext_vector_type(8)));
typedef float  f32x4  __attribute__((ext_vector_type(4)));

__device__ __forceinline__ unsigned short f2bf(float f) {
  unsigned u = __float_as_uint(f);
  u += 0x7FFFu + ((u >> 16) & 1u);   // RNE
  return (unsigned short)(u >> 16);
}
__device__ __forceinline__ float bf2f(unsigned short h) {
  return __uint_as_float(((unsigned)h) << 16);
}

__device__ __forceinline__ void gload_lds16(const void* g, void* l) {
  __builtin_amdgcn_global_load_lds((const __attribute__((address_space(1))) void*)g,
                                   (__attribute__((address_space(3))) void*)l,
                                   16, 0, 0);
}

// ---------------- fused fp32 -> bf16 conversion (x, Win, Wout in one launch) ----------------
#define NX4  (M_ * K_ / 4)          // 8388608
#define NW4  (3072 * K_ / 4)        //  786432
#define NO4  (D_ * K_ / 4)          //  262144
__global__ __launch_bounds__(256) void cvt_all(const float* __restrict__ x,
                                               const float* __restrict__ Win,
                                               const float* __restrict__ Wout,
                                               unsigned short* __restrict__ x_b,
                                               unsigned short* __restrict__ Win_b,
                                               unsigned short* __restrict__ Wout_b) {
  int i = blockIdx.x * 256 + threadIdx.x;
  const float* src;
  unsigned short* dst;
  int off;
  if (i < NX4)            { src = x;    dst = x_b;    off = i; }
  else if (i < NX4 + NW4) { src = Win;  dst = Win_b;  off = i - NX4; }
  else                    { src = Wout; dst = Wout_b; off = i - NX4 - NW4; }
  float4 v = ((const float4*)src)[off];
  ushort4 o;
  o.x = f2bf(v.x); o.y = f2bf(v.y); o.z = f2bf(v.z); o.w = f2bf(v.w);
  ((ushort4*)dst)[off] = o;
}

// ---------------- unified in_proj GEMM ----------------
// grid 6144 linear, XCD-swizzled: xcd=g&7, u=g>>3, rowtile = xcd+8*(u/24), c=u%24.
// c<16 : paired tile, B = [W_B rows c*64.. ; W_x rows c*64..]; epilogue Bx=(Bg+b)(xg+b)
// c>=16: plain tile,  B = W_C rows (c-16)*128..;              epilogue Cg=acc+b
__global__ __launch_bounds__(256) void gemm_inproj(const unsigned short* __restrict__ A,
                                                   const unsigned short* __restrict__ Wb,
                                                   const float* __restrict__ bin,
                                                   unsigned short* __restrict__ Bx,
                                                   unsigned short* __restrict__ Cg) {
  __shared__ __align__(16) char smem[16896];
  unsigned short* As = (unsigned short*)smem;
  unsigned short* Bs = (unsigned short*)(smem + 8192);
  float* tr = (float*)smem;                    // epilogue: 32 x 132 fp32

  const int g   = blockIdx.x;
  const int xcd = g & 7;
  const int u   = g >> 3;
  const int m0  = (xcd + 8 * (u / 24)) * 128;
  const int c   = u % 24;
  const int paired = (c < 16);

  const int tid  = threadIdx.x;
  const int lane = tid & 63;
  const int wave = tid >> 6;
  const int quad = lane >> 4;
  const int l16  = lane & 15;
  const int wm   = wave & 1;
  const int wn   = wave >> 1;

  int n0;
  const unsigned short* B0p;
  const unsigned short* B1p;
  if (paired) {
    n0  = c * 64;
    B0p = Wb + (long)n0 * K_;                  // W_B rows
    B1p = Wb + (long)(2048 + n0) * K_;         // W_x rows
  } else {
    n0  = (c - 16) * 128;
    B0p = Wb + (long)(1024 + n0) * K_;         // W_C rows
    B1p = B0p + (long)64 * K_;
  }

  const int r0 = tid >> 2;
  const int s0 = (tid & 3) * 8;
  const unsigned short* a0 = A + (long)(m0 + r0) * K_ + s0;
  const unsigned short* a1 = a0 + (long)64 * K_;
  const unsigned short* b0 = B0p + (long)r0 * K_ + s0;
  const unsigned short* b1 = B1p + (long)r0 * K_ + s0;
  unsigned short* lA0 = &As[tid * 8];
  unsigned short* lA1 = &As[(256 + tid) * 8];
  unsigned short* lB0 = &Bs[tid * 8];
  unsigned short* lB1 = &Bs[(256 + tid) * 8];

  f32x4 acc[4][4] = {};

  for (int k0 = 0; k0 < K_; k0 += BK) {
    gload_lds16(a0 + k0, lA0);
    gload_lds16(a1 + k0, lA1);
    gload_lds16(b0 + k0, lB0);
    gload_lds16(b1 + k0, lB1);
    __syncthreads();

    bf16x8 af[4], bfr[4];
#pragma unroll
    for (int mi = 0; mi < 4; ++mi)
      af[mi] = *(const bf16x8*)&As[(wm * 64 + mi * 16 + l16) * BK + quad * 8];
#pragma unroll
    for (int ni = 0; ni < 4; ++ni)
      bfr[ni] = *(const bf16x8*)&Bs[(wn * 64 + ni * 16 + l16) * BK + quad * 8];

#pragma unroll
    for (int mi = 0; mi < 4; ++mi)
#pragma unroll
      for (int ni = 0; ni < 4; ++ni)
        acc[mi][ni] = __builtin_amdgcn_mfma_f32_16x16x32_bf16(af[mi], bfr[ni],
                                                              acc[mi][ni], 0, 0, 0);
    __syncthreads();
  }

  // bias per write-side column
  float bv[4];
#pragma unroll
  for (int ni = 0; ni < 4; ++ni) {
    int col = wn * 64 + ni * 16 + l16;
    if (paired)
      bv[ni] = (col < 64) ? bin[n0 + col] : bin[2048 + n0 + col - 64];
    else
      bv[ni] = bin[1024 + n0 + col];
  }

  const int rr   = tid >> 3;
  const int cgid = tid & 7;

#pragma unroll
  for (int mi = 0; mi < 4; ++mi) {
#pragma unroll
    for (int ni = 0; ni < 4; ++ni) {
      int col = wn * 64 + ni * 16 + l16;
      f32x4 v = acc[mi][ni];
#pragma unroll
      for (int r = 0; r < 4; ++r)
        tr[(wm * 16 + quad * 4 + r) * 132 + col] = v[r] + bv[ni];
    }
    __syncthreads();

    int grow = m0 + (rr >> 4) * 64 + mi * 16 + (rr & 15);

    if (paired) {
#pragma unroll
      for (int j = 0; j < 2; ++j) {
        int cc = (cgid + j * 8) * 4;
        f32x4 bg = *(const f32x4*)&tr[rr * 132 + cc];
        f32x4 xg = *(const f32x4*)&tr[rr * 132 + 64 + cc];
        ushort4 o;
        o.x = f2bf(bg[0] * xg[0]); o.y = f2bf(bg[1] * xg[1]);
        o.z = f2bf(bg[2] * xg[2]); o.w = f2bf(bg[3] * xg[3]);
        *(ushort4*)&Bx[(long)grow * D_ + n0 + cc] = o;
      }
    } else {
#pragma unroll
      for (int j = 0; j < 4; ++j) {
        int cc = (cgid + j * 8) * 4;
        f32x4 v = *(const f32x4*)&tr[rr * 132 + cc];
        ushort4 o;
        o.x = f2bf(v[0]); o.y = f2bf(v[1]); o.z = f2bf(v[2]); o.w = f2bf(v[3]);
        *(ushort4*)&Cg[(long)grow * D_ + n0 + cc] = o;
      }
    }
    __syncthreads();
  }
}

// ---------------- streaming causal conv + gate ----------------
// y[b,l,d] = Cg[b,l,d] * (w[d][0]*Bx[l-2] + w[d][1]*Bx[l-1] + w[d][2]*Bx[l])
__global__ __launch_bounds__(256) void conv_mul(const unsigned short* __restrict__ Bx,
                                                const unsigned short* __restrict__ Cg,
                                                const float* __restrict__ wconv,
                                                unsigned short* __restrict__ y) {
  __shared__ float wt[3][D_];
  for (int i = threadIdx.x; i < D_; i += 256) {
    wt[0][i] = wconv[i * 3 + 0];
    wt[1][i] = wconv[i * 3 + 1];
    wt[2][i] = wconv[i * 3 + 2];
  }
  __syncthreads();

  int idx = blockIdx.x * 256 + threadIdx.x;   // [0, 32768*128)
  int bl  = idx >> 7;
  int d8  = (idx & 127) * 8;
  int l   = bl & (LSEQ - 1);

  typedef unsigned short us8 __attribute__((ext_vector_type(8)));
  us8 zz = {0, 0, 0, 0, 0, 0, 0, 0};
  us8 x0 = *(const us8*)&Bx[(long)bl * D_ + d8];
  us8 x1 = (l >= 1) ? *(const us8*)&Bx[(long)(bl - 1) * D_ + d8] : zz;
  us8 x2 = (l >= 2) ? *(const us8*)&Bx[(long)(bl - 2) * D_ + d8] : zz;
  us8 cg = *(const us8*)&Cg[(long)bl * D_ + d8];

  us8 o;
#pragma unroll
  for (int j = 0; j < 8; ++j) {
    float conv = wt[0][d8 + j] * bf2f(x2[j]) + wt[1][d8 + j] * bf2f(x1[j])
               + wt[2][d8 + j] * bf2f(x0[j]);
    o[j] = f2bf(bf2f(cg[j]) * conv);
  }
  *(us8*)&y[(long)bl * D_ + d8] = o;
}

// ---------------- out_proj GEMM (fp32 out) ----------------
// grid 2048 linear, XCD-swizzled: rowtile = (g&7) + 8*((g>>3)/8), c = (g>>3)%8
__global__ __launch_bounds__(256) void gemm_out(const unsigned short* __restrict__ A,
                                                const unsigned short* __restrict__ Wb,
                                                const float* __restrict__ bias,
                                                float* __restrict__ Out) {
  __shared__ __align__(16) char smem[16896];
  unsigned short* As = (unsigned short*)smem;
  unsigned short* Bs = (unsigned short*)(smem + 8192);
  float* tr = (float*)smem;

  const int g   = blockIdx.x;
  const int u   = g >> 3;
  const int m0  = ((g & 7) + 8 * (u >> 3)) * 128;
  const int n0  = (u & 7) * 128;

  const int tid  = threadIdx.x;
  const int lane = tid & 63;
  const int wave = tid >> 6;
  const int quad = lane >> 4;
  const int l16  = lane & 15;
  const int wm   = wave & 1;
  const int wn   = wave >> 1;

  const int r0 = tid >> 2;
  const int s0 = (tid & 3) * 8;
  const unsigned short* a0 = A + (long)(m0 + r0) * K_ + s0;
  const unsigned short* a1 = a0 + (long)64 * K_;
  const unsigned short* b0 = Wb + (long)(n0 + r0) * K_ + s0;
  const unsigned short* b1 = b0 + (long)64 * K_;
  unsigned short* lA0 = &As[tid * 8];
  unsigned short* lA1 = &As[(256 + tid) * 8];
  unsigned short* lB0 = &Bs[tid * 8];
  unsigned short* lB1 = &Bs[(256 + tid) * 8];

  f32x4 acc[4][4] = {};

  for (int k0 = 0; k0 < K_; k0 += BK) {
    gload_lds16(a0 + k0, lA0);
    gload_lds16(a1 + k0, lA1);
    gload_lds16(b0 + k0, lB0);
    gload_lds16(b1 + k0, lB1);
    __syncthreads();

    bf16x8 af[4], bfr[4];
#pragma unroll
    for (int mi = 0; mi < 4; ++mi)
      af[mi] = *(const bf16x8*)&As[(wm * 64 + mi * 16 + l16) * BK + quad * 8];
#pragma unroll
    for (int ni = 0; ni < 4; ++ni)
      bfr[ni] = *(const bf16x8*)&Bs[(wn * 64 + ni * 16 + l16) * BK + quad * 8];

#pragma unroll
    for (int mi = 0; mi < 4; ++mi)
#pragma unroll
      for (int ni = 0; ni < 4; ++ni)
        acc[mi][ni] = __builtin_amdgcn_mfma_f32_16x16x32_bf16(af[mi], bfr[ni],
                                                              acc[mi][ni], 0, 0, 0);
    __syncthreads();
  }

  float bv[4];
#pragma unroll
  for (int ni = 0; ni < 4; ++ni)
    bv[ni] = bias[n0 + wn * 64 + ni * 16 + l16];

  const int rr   = tid >> 3;
  const int cgid = tid & 7;

#pragma unroll
  for (int mi = 0; mi < 4; ++mi) {
#pragma unroll
    for (int ni = 0; ni < 4; ++ni) {
      int col = wn * 64 + ni * 16 + l16;
      f32x4 v = acc[mi][ni];
#pragma unroll
      for (int r = 0; r < 4; ++r)
        tr[(wm * 16 + quad * 4 + r) * 132 + col] = v[r] + bv[ni];
    }
    __syncthreads();

    int grow = m0 + (rr >> 4) * 64 + mi * 16 + (rr & 15);
#pragma unroll
    for (int j = 0; j < 4; ++j) {
      int cc = (cgid + j * 8) * 4;
      f32x4 v = *(const f32x4*)&tr[rr * 132 + cc];
      *(f32x4*)&Out[(long)grow * D_ + n0 + cc] = v;
    }
    __syncthreads();
  }
}

// ---------------- launch ----------------
extern "C" void kernel_launch(void* const* d_in, const int* in_sizes, int n_in,
                              void* d_out, int out_size, void* d_ws, size_t ws_size,
                              hipStream_t stream) {
  const float* x     = (const float*)d_in[0];
  const float* Win   = (const float*)d_in[1];
  const float* bin   = (const float*)d_in[2];
  const float* wconv = (const float*)d_in[3];
  const float* Wout  = (const float*)d_in[4];
  const float* bout  = (const float*)d_in[5];

  char* ws = (char*)d_ws;
  // ws: x_b 67,108,864 | Win_b 6,291,456 | Wout_b 2,097,152 | Bx 67,108,864 | Cg 67,108,864 | y 67,108,864
  unsigned short* x_b    = (unsigned short*)(ws);
  unsigned short* Win_b  = (unsigned short*)(ws + 67108864);
  unsigned short* Wout_b = (unsigned short*)(ws + 73400320);
  unsigned short* Bx_b   = (unsigned short*)(ws + 75497472);
  unsigned short* Cg_b   = (unsigned short*)(ws + 142606336);
  unsigned short* y_b    = (unsigned short*)(ws + 209715200);

  cvt_all<<<(NX4 + NW4 + NO4) / 256, 256, 0, stream>>>(x, Win, Wout, x_b, Win_b, Wout_b);

  gemm_inproj<<<6144, 256, 0, stream>>>(x_b, Win_b, bin, Bx_b, Cg_b);

  conv_mul<<<(M_ * (D_ / 8)) / 256, 256, 0, stream>>>(Bx_b, Cg_b, wconv, y_b);

  gemm_out<<<2048, 256, 0, stream>>>(y_b, Wout_b, bout, (float*)d_out);
}